// Round 6
// baseline (172.161 us; speedup 1.0000x reference)
//
#include <hip/hip_runtime.h>

#define NUM_USER 100000
#define K_NEIGH 32
#define DIM 64
#define NSLICE 4                       // dim slices; slice = blockIdx % 4 -> fixed XCD (XCD = blockIdx % 8)
#define SLICE_DIMS 16                  // dims per slice
#define SLICE_U32 (NUM_USER * 8)       // uints per slice: 8 uints = 16 bf16 dims per user row (32 B)
#define USERS_PER_BLOCK 32             // 256 threads / 8 lanes per user-slice

typedef float floatx2 __attribute__((ext_vector_type(2)));
typedef float floatx4 __attribute__((ext_vector_type(4)));
typedef int   intx4   __attribute__((ext_vector_type(4)));

__device__ __forceinline__ unsigned int pack_bf16(float a, float b) {
  unsigned int ua = __float_as_uint(a), ub = __float_as_uint(b);
  // round-to-nearest-even to bf16
  unsigned int ra = (ua + 0x7fffu + ((ua >> 16) & 1u)) >> 16;
  unsigned int rb = (ub + 0x7fffu + ((ub >> 16) & 1u)) >> 16;
  return ra | (rb << 16);
}

// ---------------------------------------------------------------------------
// Session model (rounds 0-5):
//  * Harness overhead ~76us CONSTANT; only total kernel time matters.
//  * Gather is bound by the L2-MISS path for random 128B lines: 159MB/47.5us
//    = 3.35 TB/s (bf16), 349MB/91us = 3.83 TB/s (f32). Instruction-count
//    tricks are nearly exhausted (LDS staging bought only 51->47.5us).
//  * Fix this round: dim-sliced table so each XCD's L2 holds its whole slice
//    (3.2MB < 4MB). slice = blockIdx%4 rides the round-robin XCD mapping.
//    Table re-reads become L2 hits; replaced traffic is streaming graph/
//    matrix re-reads (4x25.6MB, L3-resident).
//  * r5: __builtin_nontemporal_load requires clang ext_vector types, NOT
//    HIP_vector_type (int4) -> use intx4/floatx4 typedefs.
// ---------------------------------------------------------------------------

// Kernel 1: fp32 features -> slice-major packed bf16 table in d_ws.
// table[s*SLICE_U32 + u*8 + j] packs dims {s*16+2j, s*16+2j+1} of user u.
// grid = (NUM_USER*8/256, NSLICE); writes perfectly coalesced per block.
__global__ __launch_bounds__(256) void convert_sliced_kernel(
    const floatx2* __restrict__ feat2,    // features as float2 [NUM_USER*32]
    unsigned int*  __restrict__ table) {
  const int s = blockIdx.y;
  const int t = blockIdx.x * 256 + threadIdx.x;   // 0 .. NUM_USER*8-1
  const int u = t >> 3;
  const int j = t & 7;
  floatx2 f = __builtin_nontemporal_load(feat2 + u * 32 + s * 8 + j);
  table[s * SLICE_U32 + t] = pack_bf16(f.x, f.y);
}

// Kernel 2: gather + weighted sum for ONE dim-slice per block.
// 8 lanes per user-slice (lane dl owns dims {s*16+2dl, s*16+2dl+1});
// 32 users per block; {idx*8, w} staged in padded LDS (row stride 33 pairs
// = 264B -> conflict-free broadcast reads).
__global__ __launch_bounds__(256) void gather_sliced_kernel(
    const unsigned int* __restrict__ table,    // sliced bf16 table
    const intx4*        __restrict__ graph4,   // graph as intx4  [NUM_USER*8]
    const floatx4*      __restrict__ matrix4,  // matrix as floatx4 [NUM_USER*8]
    floatx2*            __restrict__ out2) {   // [NUM_USER][32] float2
  __shared__ int2 pairs[USERS_PER_BLOCK][K_NEIGH + 1];  // pad -> no conflicts

  const int s  = blockIdx.x & (NSLICE - 1);   // slice == XCD % 4
  const int ub = blockIdx.x >> 2;             // user-block 0..3124
  const int e  = threadIdx.x;                 // 0..255

  // Stage 32 users' {idx,w}: thread e covers user e>>3, k = (e&7)*4 .. +3.
  // idx pre-scaled to uint-row offset (idx*8) to shrink k-loop address math.
  intx4   g4 = __builtin_nontemporal_load(graph4  + ub * 256 + e);
  floatx4 w4 = __builtin_nontemporal_load(matrix4 + ub * 256 + e);
  {
    const int su = e >> 3, k0 = (e & 7) * 4;
    pairs[su][k0 + 0] = make_int2(g4.x * 8, __float_as_int(w4.x));
    pairs[su][k0 + 1] = make_int2(g4.y * 8, __float_as_int(w4.y));
    pairs[su][k0 + 2] = make_int2(g4.z * 8, __float_as_int(w4.z));
    pairs[su][k0 + 3] = make_int2(g4.w * 8, __float_as_int(w4.w));
  }
  __syncthreads();

  const int ul = e >> 3;                      // user slot 0..31
  const int dl = e & 7;                       // uint lane in the 32B slice row
  const unsigned int* tb = table + s * SLICE_U32 + dl;
  const int2* prow = pairs[ul];

  float acc0 = 0.f, acc1 = 0.f;
#pragma unroll
  for (int k = 0; k < K_NEIGH; ++k) {
    int2  pr = prow[k];                       // broadcast ds_read_b64
    float wk = __int_as_float(pr.y);
    unsigned int p = tb[pr.x];                // 8 lanes x 4B = 32B/user row (L2-hit)
    acc0 += wk * __uint_as_float(p << 16);          // dim s*16 + 2*dl
    acc1 += wk * __uint_as_float(p & 0xffff0000u);  // dim s*16 + 2*dl + 1
  }

  const int u = ub * USERS_PER_BLOCK + ul;
  floatx2 r; r.x = acc0; r.y = acc1;
  __builtin_nontemporal_store(r, out2 + u * 32 + s * 8 + dl);  // 64B/user-slice
}

// ---------------------------------------------------------------------------
// Fallback (no ws space): round-3 single-kernel f32 gather, known-good 100us.
// ---------------------------------------------------------------------------
__global__ __launch_bounds__(256) void gather_f32_lds_kernel(
    const floatx2* __restrict__ feat2,
    const int*     __restrict__ graph,
    const float*   __restrict__ matrix,
    floatx2*       __restrict__ out2) {
  __shared__ int2 pairsf[8 * K_NEIGH];
  const int e    = threadIdx.x;
  const int base = blockIdx.x * (8 * K_NEIGH);
  int   gv = __builtin_nontemporal_load(graph  + base + e);
  float wv = __builtin_nontemporal_load(matrix + base + e);
  pairsf[e] = make_int2(gv, __float_as_int(wv));
  __syncthreads();
  const int u_local = e >> 5;
  const int d2      = e & 31;
  const int2* prow  = pairsf + u_local * K_NEIGH;
  float acc0 = 0.f, acc1 = 0.f;
#pragma unroll
  for (int k = 0; k < K_NEIGH; ++k) {
    int2  pr = prow[k];
    float wk = __int_as_float(pr.y);
    floatx2 p = feat2[pr.x * 32 + d2];
    acc0 += wk * p.x;
    acc1 += wk * p.y;
  }
  floatx2 r; r.x = acc0; r.y = acc1;
  __builtin_nontemporal_store(r, out2 + base + e);
}

extern "C" void kernel_launch(void* const* d_in, const int* in_sizes, int n_in,
                              void* d_out, int out_size, void* d_ws, size_t ws_size,
                              hipStream_t stream) {
  const float* features = (const float*)d_in[0];
  const int*   graph    = (const int*)d_in[1];
  const float* matrix   = (const float*)d_in[2];

  const size_t table_bytes = (size_t)NUM_USER * DIM * 2;  // 12.8 MB bf16
  if (ws_size >= table_bytes) {
    unsigned int* table = (unsigned int*)d_ws;
    // Convert: 800000 uints per slice / 256 = 3125 blocks, y = slice.
    dim3 cgrid(NUM_USER * 8 / 256, NSLICE);
    convert_sliced_kernel<<<cgrid, 256, 0, stream>>>(
        (const floatx2*)features, table);
    // Gather: 3125 user-blocks x 4 slices = 12500 blocks (no tail).
    gather_sliced_kernel<<<(NUM_USER / USERS_PER_BLOCK) * NSLICE, 256, 0, stream>>>(
        table, (const intx4*)graph, (const floatx4*)matrix, (floatx2*)d_out);
  } else {
    gather_f32_lds_kernel<<<NUM_USER / 8, 256, 0, stream>>>(
        (const floatx2*)features, graph, matrix, (floatx2*)d_out);
  }
}

// Round 7
// 135.532 us; speedup vs baseline: 1.2703x; 1.2703x over previous
//
#include <hip/hip_runtime.h>

#define NUM_USER 100000
#define K_NEIGH 32
#define DIM 64
#define USERS_PER_BLOCK 8   // 256 threads / 32 lanes per user

typedef float floatx2 __attribute__((ext_vector_type(2)));
typedef float floatx4 __attribute__((ext_vector_type(4)));
typedef unsigned int uintx4 __attribute__((ext_vector_type(4)));

__device__ __forceinline__ unsigned int pack_bf16(float a, float b) {
  unsigned int ua = __float_as_uint(a), ub = __float_as_uint(b);
  // round-to-nearest-even to bf16
  unsigned int ra = (ua + 0x7fffu + ((ua >> 16) & 1u)) >> 16;
  unsigned int rb = (ub + 0x7fffu + ((ub >> 16) & 1u)) >> 16;
  return ra | (rb << 16);
}

// ---------------------------------------------------------------------------
// Session model (rounds 0-6):
//  * Harness overhead ~76us CONSTANT; only total kernel time matters.
//  * The gather's currency is RANDOM LINE-REQUEST COUNT, not bytes:
//      r3 f32  (2 lines/user-row): 6.4M req -> 91.0us  (70 G req/s)
//      r4 bf16 (1 line/user-row):  3.2M req -> 47.5us  (67 G req/s)
//      r6 dim-sliced (32B rows):  12.8M req -> 80.6us  (even L2-resident!)
//    => full-128B-line per user row (bf16, 32 lanes/user) is the request
//       floor. Dim-slicing for L2 residency is a confirmed dead end.
//  * r4 ran at 3.35 TB/s miss-path vs r3's demonstrated 3.83 TB/s with 2x
//    outstanding requests, and r4's VGPR=32 is the allocator floor ->
//    this round: register-batched window of 8 in-flight gathers per lane
//    (static arrays + full unroll = registers; <=64 VGPR keeps occupancy).
//  * LDS {idx*32, w} staging proven free (r3/r4); idx pre-scaled at staging.
// ---------------------------------------------------------------------------

// Kernel 1: fp32 features -> packed bf16x2 table in d_ws.
// Thread i handles 8 floats (32B read, 16B write), fully coalesced.
__global__ __launch_bounds__(256) void convert_bf16_kernel(
    const floatx4* __restrict__ feat4,   // 1.6M float4
    uintx4*        __restrict__ table4) {// 800K uintx4
  int i = blockIdx.x * 256 + threadIdx.x;
  floatx4 f0 = __builtin_nontemporal_load(feat4 + i * 2);
  floatx4 f1 = __builtin_nontemporal_load(feat4 + i * 2 + 1);
  uintx4 r;
  r.x = pack_bf16(f0.x, f0.y);
  r.y = pack_bf16(f0.z, f0.w);
  r.z = pack_bf16(f1.x, f1.y);
  r.w = pack_bf16(f1.z, f1.w);
  table4[i] = r;  // normal store: table is re-read next kernel, keep in L2
}

// Kernel 2: gather+weighted-sum from the bf16 table, LDS-staged {idx,w},
// register-batched 8-deep gather window for MLP.
// 32 lanes per user (2 users/wave); lane d2 owns dims {2*d2, 2*d2+1}.
__global__ __launch_bounds__(256) void gather_bf16_lds_kernel(
    const unsigned int* __restrict__ table,   // [NUM_USER][32] bf16x2
    const int*          __restrict__ graph,   // [NUM_USER][32]
    const float*        __restrict__ matrix,  // [NUM_USER][32]
    floatx2*            __restrict__ out2) {  // [NUM_USER][32] float2
  __shared__ int2 pairs[USERS_PER_BLOCK * K_NEIGH];  // {idx*32, w_bits}, 2 KiB

  const int e    = threadIdx.x;        // 0..255
  const int base = blockIdx.x * 256;   // element offset (users*32)

  // Stage this block's 8 users' graph+matrix rows; pre-scale idx to row base.
  int   gv = __builtin_nontemporal_load(graph  + base + e);
  float wv = __builtin_nontemporal_load(matrix + base + e);
  pairs[e] = make_int2(gv * 32, __float_as_int(wv));
  __syncthreads();

  const int d2     = e & 31;                        // dims {2*d2, 2*d2+1}
  const int2* prow = pairs + (e >> 5) * K_NEIGH;
  const unsigned int* tb = table + d2;

  float acc0 = 0.f, acc1 = 0.f;
#pragma unroll
  for (int kb = 0; kb < K_NEIGH / 8; ++kb) {
    // phase 1: issue 8 independent gathers (stay in registers: static idx)
    unsigned int pv[8];
    float        wk[8];
#pragma unroll
    for (int j = 0; j < 8; ++j) {
      int2 pr = prow[kb * 8 + j];        // broadcast ds_read_b64, LDS pipe
      wk[j] = __int_as_float(pr.y);
      pv[j] = tb[pr.x];                  // 32 lanes x 4B = one 128B line
    }
    // phase 2: consume
#pragma unroll
    for (int j = 0; j < 8; ++j) {
      acc0 += wk[j] * __uint_as_float(pv[j] << 16);          // dim 2*d2
      acc1 += wk[j] * __uint_as_float(pv[j] & 0xffff0000u);  // dim 2*d2+1
    }
  }
  floatx2 r; r.x = acc0; r.y = acc1;
  // out offset: u*32+d2 == base + e
  __builtin_nontemporal_store(r, out2 + base + e);  // 8B/lane coalesced
}

// ---------------------------------------------------------------------------
// Fallback (no ws space): round-3 single-kernel f32 gather, known-good 100us.
// ---------------------------------------------------------------------------
__global__ __launch_bounds__(256) void gather_f32_lds_kernel(
    const floatx2* __restrict__ feat2,
    const int*     __restrict__ graph,
    const float*   __restrict__ matrix,
    floatx2*       __restrict__ out2) {
  __shared__ int2 pairsf[USERS_PER_BLOCK * K_NEIGH];
  const int e    = threadIdx.x;
  const int base = blockIdx.x * 256;
  int   gv = __builtin_nontemporal_load(graph  + base + e);
  float wv = __builtin_nontemporal_load(matrix + base + e);
  pairsf[e] = make_int2(gv, __float_as_int(wv));
  __syncthreads();
  const int u_local = e >> 5;
  const int d2      = e & 31;
  const int2* prow  = pairsf + u_local * K_NEIGH;
  float acc0 = 0.f, acc1 = 0.f;
#pragma unroll
  for (int k = 0; k < K_NEIGH; ++k) {
    int2  pr = prow[k];
    float wk = __int_as_float(pr.y);
    floatx2 p = feat2[pr.x * 32 + d2];
    acc0 += wk * p.x;
    acc1 += wk * p.y;
  }
  floatx2 r; r.x = acc0; r.y = acc1;
  __builtin_nontemporal_store(r, out2 + base + e);
}

extern "C" void kernel_launch(void* const* d_in, const int* in_sizes, int n_in,
                              void* d_out, int out_size, void* d_ws, size_t ws_size,
                              hipStream_t stream) {
  const float* features = (const float*)d_in[0];
  const int*   graph    = (const int*)d_in[1];
  const float* matrix   = (const float*)d_in[2];

  const size_t table_bytes = (size_t)NUM_USER * DIM * 2;  // 12.8 MB bf16
  if (ws_size >= table_bytes) {
    unsigned int* table = (unsigned int*)d_ws;
    // Convert: 800000 uintx4 / 256 = 3125 blocks exactly.
    convert_bf16_kernel<<<NUM_USER * DIM / 8 / 256, 256, 0, stream>>>(
        (const floatx4*)features, (uintx4*)table);
    // Gather: 100000 users / 8 per block = 12500 blocks exactly.
    gather_bf16_lds_kernel<<<NUM_USER / USERS_PER_BLOCK, 256, 0, stream>>>(
        table, graph, matrix, (floatx2*)d_out);
  } else {
    gather_f32_lds_kernel<<<NUM_USER / USERS_PER_BLOCK, 256, 0, stream>>>(
        (const floatx2*)features, graph, matrix, (floatx2*)d_out);
  }
}